// Round 1
// baseline (337.635 us; speedup 1.0000x reference)
//
#include <hip/hip_runtime.h>

// self_attention: x(4,2048,1024) fp32; Q=xWq^T+bq, K=xWk^T+bk, V=xWv^T+bv
// logits = QK^T / sqrt(2048)  (NOTE: seq_len, faithful to reference)
// out = softmax(logits) @ V
//
// Pipeline (all bf16 MFMA 16x16x32, fp32 accumulate):
//   K0: cast x,Wq,Wk,Wv -> bf16
//   K1: Q,K bf16 row-major; V^T bf16 (per-batch transpose) via GEMM-BT
//   K2: scores = Q K^T * 1/sqrt(2048) -> bf16
//   K3: row softmax in place
//   K4: out = att @ (V^T)^T -> fp32
//
// GEMM structure = verified m93/m97 ladder: 128x128 tile, BK=32, 256 thr
// (4 waves, each 4x4 MFMA tiles of 16x16), global_load_lds width=16 staging.

typedef unsigned short u16;
typedef unsigned int u32;
typedef __bf16 bf16x8 __attribute__((ext_vector_type(8)));
typedef float floatx4 __attribute__((ext_vector_type(4)));

__device__ __forceinline__ u16 f2bf(float f) {
    u32 u = __float_as_uint(f);
    u += 0x7fffu + ((u >> 16) & 1u);   // RNE
    return (u16)(u >> 16);
}

__device__ __forceinline__ void g2lds16(const void* g, void* l) {
    __builtin_amdgcn_global_load_lds(
        (const __attribute__((address_space(1))) unsigned int*)g,
        (__attribute__((address_space(3))) unsigned int*)l,
        16, 0, 0);
}

// ---------------- cast fp32 -> bf16, 4 elems/thread ----------------
__global__ __launch_bounds__(256)
void cvt_f32_bf16(const float* __restrict__ in, u16* __restrict__ out, int n4) {
    int i = blockIdx.x * 256 + threadIdx.x;
    if (i >= n4) return;
    float4 v = ((const float4*)in)[i];
    ushort4 o;
    o.x = f2bf(v.x); o.y = f2bf(v.y); o.z = f2bf(v.z); o.w = f2bf(v.w);
    ((ushort4*)out)[i] = o;
}

// ---------------- GEMM: C[m][n] = sum_k A[m][k] * B[n][k] ----------------
// A: M x K row-major bf16, B: N x K row-major bf16 (i.e. B^T layout).
// MODE 0: bf16 out row-major (ld=N). MODE 1: bf16 out transposed (out[n*M+m]).
// MODE 2: fp32 out row-major (ld=N).  val = acc*scale + bias[n]
template<int MODE>
__global__ __launch_bounds__(256)
void gemm_bt(const u16* __restrict__ A, const u16* __restrict__ B,
             void* __restrict__ Out, const float* __restrict__ bias,
             float scale, int M, int N, int K,
             long long sAz, long long sBz, long long sOz)
{
    __shared__ u16 ldsA[128 * 32];
    __shared__ u16 ldsB[128 * 32];

    const int tid   = threadIdx.x;
    const int lane  = tid & 63;
    const int wv    = tid >> 6;          // wave 0..3
    const int wm    = (wv >> 1) * 64;    // wave tile row offset
    const int wn    = (wv & 1) * 64;     // wave tile col offset
    const int lhalf = lane & 15;
    const int quad  = lane >> 4;

    const size_t bz = blockIdx.z;
    A += bz * (size_t)sAz;
    B += bz * (size_t)sBz;

    const int m0 = blockIdx.y * 128;
    const int n0 = blockIdx.x * 128;

    // staging: chunk c = t*256 + tid covers row c>>2, k-offset (c&3)*8
    const int rowA = tid >> 2;               // 0..63
    const int kofs = (tid & 3) * 8;
    const u16* pa = A + (size_t)(m0 + rowA) * K + kofs;
    const u16* pb = B + (size_t)(n0 + rowA) * K + kofs;
    u16* la = &ldsA[wv * 512];               // wave-uniform LDS base
    u16* lb = &ldsB[wv * 512];

    floatx4 zero = {0.f, 0.f, 0.f, 0.f};
    floatx4 acc[4][4];
#pragma unroll
    for (int i = 0; i < 4; ++i)
#pragma unroll
        for (int j = 0; j < 4; ++j) acc[i][j] = zero;

    for (int k0 = 0; k0 < K; k0 += 32) {
        __syncthreads();                     // prev iter's LDS reads done
        g2lds16(pa,                 la);
        g2lds16(pa + (size_t)64 * K, la + 2048);
        g2lds16(pb,                 lb);
        g2lds16(pb + (size_t)64 * K, lb + 2048);
        pa += 32; pb += 32;
        __syncthreads();                     // drains vmcnt -> LDS valid

        bf16x8 af[4], bf[4];
#pragma unroll
        for (int i = 0; i < 4; ++i)
            af[i] = *(const bf16x8*)(ldsA + (wm + i * 16 + lhalf) * 32 + quad * 8);
#pragma unroll
        for (int j = 0; j < 4; ++j)
            bf[j] = *(const bf16x8*)(ldsB + (wn + j * 16 + lhalf) * 32 + quad * 8);
#pragma unroll
        for (int i = 0; i < 4; ++i)
#pragma unroll
            for (int j = 0; j < 4; ++j)
                acc[i][j] = __builtin_amdgcn_mfma_f32_16x16x32_bf16(
                    af[i], bf[j], acc[i][j], 0, 0, 0);
    }

    // epilogue: C/D layout col=lane&15 (n), row=quad*4+reg (m)  [m89/m91]
#pragma unroll
    for (int i = 0; i < 4; ++i) {
        const int mb = m0 + wm + i * 16 + quad * 4;
#pragma unroll
        for (int j = 0; j < 4; ++j) {
            const int n = n0 + wn + j * 16 + lhalf;
            const float bb = bias ? bias[n] : 0.f;
#pragma unroll
            for (int r = 0; r < 4; ++r) {
                const int m = mb + r;
                const float v = acc[i][j][r] * scale + bb;
                if (MODE == 2) {
                    ((float*)Out)[bz * (size_t)sOz + (size_t)m * N + n] = v;
                } else if (MODE == 0) {
                    ((u16*)Out)[bz * (size_t)sOz + (size_t)m * N + n] = f2bf(v);
                } else {
                    ((u16*)Out)[bz * (size_t)sOz + (size_t)n * M + m] = f2bf(v);
                }
            }
        }
    }
}

// ---------------- row softmax over 2048 bf16, in place ----------------
__global__ __launch_bounds__(256)
void softmax_rows(u16* __restrict__ S)
{
    const int tid = threadIdx.x;
    u16* row = S + (size_t)blockIdx.x * 2048;
    uint4 v = ((const uint4*)row)[tid];     // 8 bf16 per thread
    float x[8];
    x[0] = __uint_as_float(v.x << 16); x[1] = __uint_as_float(v.x & 0xffff0000u);
    x[2] = __uint_as_float(v.y << 16); x[3] = __uint_as_float(v.y & 0xffff0000u);
    x[4] = __uint_as_float(v.z << 16); x[5] = __uint_as_float(v.z & 0xffff0000u);
    x[6] = __uint_as_float(v.w << 16); x[7] = __uint_as_float(v.w & 0xffff0000u);

    float mx = x[0];
#pragma unroll
    for (int i = 1; i < 8; ++i) mx = fmaxf(mx, x[i]);
#pragma unroll
    for (int off = 32; off > 0; off >>= 1) mx = fmaxf(mx, __shfl_xor(mx, off, 64));

    __shared__ float sm[4], ss[4];
    if ((tid & 63) == 0) sm[tid >> 6] = mx;
    __syncthreads();
    mx = fmaxf(fmaxf(sm[0], sm[1]), fmaxf(sm[2], sm[3]));

    float e[8];
    float s = 0.f;
#pragma unroll
    for (int i = 0; i < 8; ++i) { e[i] = __expf(x[i] - mx); s += e[i]; }
#pragma unroll
    for (int off = 32; off > 0; off >>= 1) s += __shfl_xor(s, off, 64);
    if ((tid & 63) == 0) ss[tid >> 6] = s;
    __syncthreads();
    s = (ss[0] + ss[1]) + (ss[2] + ss[3]);

    const float inv = 1.f / s;
    uint4 o;
    o.x = (u32)f2bf(e[0] * inv) | ((u32)f2bf(e[1] * inv) << 16);
    o.y = (u32)f2bf(e[2] * inv) | ((u32)f2bf(e[3] * inv) << 16);
    o.z = (u32)f2bf(e[4] * inv) | ((u32)f2bf(e[5] * inv) << 16);
    o.w = (u32)f2bf(e[6] * inv) | ((u32)f2bf(e[7] * inv) << 16);
    ((uint4*)row)[tid] = o;
}

extern "C" void kernel_launch(void* const* d_in, const int* in_sizes, int n_in,
                              void* d_out, int out_size, void* d_ws, size_t ws_size,
                              hipStream_t stream)
{
    const float* x  = (const float*)d_in[0];
    const float* Wq = (const float*)d_in[1];
    const float* bq = (const float*)d_in[2];
    const float* Wk = (const float*)d_in[3];
    const float* bk = (const float*)d_in[4];
    const float* Wv = (const float*)d_in[5];
    const float* bv = (const float*)d_in[6];
    float* out = (float*)d_out;

    const int B = 4, S = 2048, D = 1024;
    const long long SD = (long long)S * D;       // 2097152
    const long long SS = (long long)S * S;       // 4194304
    const long long BSD = (long long)B * SD;     // 8388608
    const long long DD = (long long)D * D;       // 1048576

    // workspace layout (bf16 = u16), total ~102 MB
    u16* xb  = (u16*)d_ws;
    u16* wqb = xb  + BSD;
    u16* wkb = wqb + DD;
    u16* wvb = wkb + DD;
    u16* Qb  = wvb + DD;
    u16* Kb  = Qb  + BSD;
    u16* Vt  = Kb  + BSD;        // per-batch transposed: Vt[b][d][s]
    u16* Sc  = Vt  + BSD;        // scores/att bf16: [b][q][k]

    // K0: casts
    cvt_f32_bf16<<<dim3((int)(BSD / 4 / 256)), 256, 0, stream>>>(x,  xb,  (int)(BSD / 4));
    cvt_f32_bf16<<<dim3((int)(DD  / 4 / 256)), 256, 0, stream>>>(Wq, wqb, (int)(DD / 4));
    cvt_f32_bf16<<<dim3((int)(DD  / 4 / 256)), 256, 0, stream>>>(Wk, wkb, (int)(DD / 4));
    cvt_f32_bf16<<<dim3((int)(DD  / 4 / 256)), 256, 0, stream>>>(Wv, wvb, (int)(DD / 4));

    // K1: Q, K row-major bf16 (M=8192), V^T per batch
    gemm_bt<0><<<dim3(D / 128, (B * S) / 128, 1), 256, 0, stream>>>(
        xb, wqb, Qb, bq, 1.f, B * S, D, D, 0, 0, 0);
    gemm_bt<0><<<dim3(D / 128, (B * S) / 128, 1), 256, 0, stream>>>(
        xb, wkb, Kb, bk, 1.f, B * S, D, D, 0, 0, 0);
    gemm_bt<1><<<dim3(D / 128, S / 128, B), 256, 0, stream>>>(
        xb, wvb, Vt, bv, 1.f, S, D, D, SD, 0, SD);

    // K2: scores = Q K^T / sqrt(S)
    const float sc = 0.022097086912079608f;  // 1/sqrt(2048)
    gemm_bt<0><<<dim3(S / 128, S / 128, B), 256, 0, stream>>>(
        Qb, Kb, Sc, nullptr, sc, S, S, D, SD, SD, SS);

    // K3: softmax rows
    softmax_rows<<<dim3(B * S), 256, 0, stream>>>(Sc);

    // K4: out = att @ V  (A = att, B = Vt rows=d, K=S)
    gemm_bt<2><<<dim3(D / 128, S / 128, B), 256, 0, stream>>>(
        Sc, Vt, out, nullptr, 1.f, S, D, S, SS, SD, SD);
}

// Round 2
// 289.250 us; speedup vs baseline: 1.1673x; 1.1673x over previous
//
#include <hip/hip_runtime.h>

// self_attention: x(4,2048,1024) fp32; Q=xWq^T+bq, K=xWk^T+bk, V=xWv^T+bv
// logits = QK^T / sqrt(2048); out = softmax(logits) @ V
//
// R2: gemm_bt v2 — BK=64 (128 B LDS rows = full bank span) + XOR chunk
// swizzle on the global source of global_load_lds so ds_read_b128 fragment
// reads are conflict-free (R1 had 8-way conflicts, SQ_LDS_BANK_CONFLICT
// clipped at 2^22). GROUP_M=4 supertile mapping for L2 tile reuse.

typedef unsigned short u16;
typedef unsigned int u32;
typedef __bf16 bf16x8 __attribute__((ext_vector_type(8)));
typedef float floatx4 __attribute__((ext_vector_type(4)));

__device__ __forceinline__ u16 f2bf(float f) {
    u32 u = __float_as_uint(f);
    u += 0x7fffu + ((u >> 16) & 1u);   // RNE
    return (u16)(u >> 16);
}

__device__ __forceinline__ void g2lds16(const void* g, void* l) {
    __builtin_amdgcn_global_load_lds(
        (const __attribute__((address_space(1))) unsigned int*)g,
        (__attribute__((address_space(3))) unsigned int*)l,
        16, 0, 0);
}

// ---------------- cast fp32 -> bf16, 4 elems/thread ----------------
__global__ __launch_bounds__(256)
void cvt_f32_bf16(const float* __restrict__ in, u16* __restrict__ out, int n4) {
    int i = blockIdx.x * 256 + threadIdx.x;
    if (i >= n4) return;
    float4 v = ((const float4*)in)[i];
    ushort4 o;
    o.x = f2bf(v.x); o.y = f2bf(v.y); o.z = f2bf(v.z); o.w = f2bf(v.w);
    ((ushort4*)out)[i] = o;
}

// ---------------- GEMM: C[m][n] = sum_k A[m][k] * B[n][k] ----------------
// A: M x K row-major bf16, B: N x K row-major bf16 (B^T layout).
// MODE 0: bf16 out row-major. MODE 1: bf16 out transposed (out[n*M+m]).
// MODE 2: fp32 out row-major.   val = acc*scale + bias[n]
// 128x128 block tile, BK=64, 4 waves each 64x64 (4x4 of 16x16x32 MFMA).
// LDS: [128 rows][64 u16] = 128 B rows; chunk (16 B) at physical index
// p = c ^ (row & 7)  -> ds_read_b128 frag reads are 2-way max (free).
template<int MODE>
__global__ __launch_bounds__(256)
void gemm_bt(const u16* __restrict__ A, const u16* __restrict__ B,
             void* __restrict__ Out, const float* __restrict__ bias,
             float scale, int M, int N, int K,
             long long sAz, long long sBz, long long sOz)
{
    __shared__ u16 ldsA[128 * 64];   // 16 KB
    __shared__ u16 ldsB[128 * 64];   // 16 KB

    const int tid   = threadIdx.x;
    const int lane  = tid & 63;
    const int wv    = tid >> 6;          // wave 0..3
    const int wm    = (wv >> 1) * 64;    // wave tile row offset
    const int wn    = (wv & 1) * 64;     // wave tile col offset
    const int lhalf = lane & 15;
    const int quad  = lane >> 4;

    const size_t bz = blockIdx.z;
    A += bz * (size_t)sAz;
    B += bz * (size_t)sBz;

    // supertile mapping (GROUP_M=4) for L2 tile reuse
    int tm, tn;
    {
        const int ntn = gridDim.x, ntm = gridDim.y;
        const int lin = blockIdx.y * ntn + blockIdx.x;
        const int GM = 4;
        const int width = GM * ntn;
        const int group = lin / width;
        const int first = group * GM;
        const int gsz   = (ntm - first) < GM ? (ntm - first) : GM;
        const int rem   = lin - group * width;
        tm = first + rem % gsz;
        tn = rem / gsz;
    }
    const int m0 = tm * 128;
    const int n0 = tn * 128;

    // staging: physical chunk P = wv*256 + j*64 + lane  (j = 0..3)
    //   row r = P>>3 = wv*32 + j*8 + (lane>>3), phys chunk p = lane&7
    //   global chunk g = p ^ (r&7) = (lane&7) ^ (lane>>3)
    const int r8 = lane >> 3;                   // 0..7
    const int gc = (lane & 7) ^ r8;             // swizzled source chunk
    const u16* pa = A + (size_t)(m0 + wv * 32 + r8) * K + gc * 8;
    const u16* pb = B + (size_t)(n0 + wv * 32 + r8) * K + gc * 8;
    u16* la = ldsA + wv * 2048;                 // wave-uniform LDS base
    u16* lb = ldsB + wv * 2048;

    floatx4 zero = {0.f, 0.f, 0.f, 0.f};
    floatx4 acc[4][4];
#pragma unroll
    for (int i = 0; i < 4; ++i)
#pragma unroll
        for (int j = 0; j < 4; ++j) acc[i][j] = zero;

    const int swz = lhalf & 7;                  // row&7 for all frag rows

    for (int k0 = 0; k0 < K; k0 += 64) {
        __syncthreads();                        // prev iter's LDS reads done
#pragma unroll
        for (int j = 0; j < 4; ++j) {
            g2lds16(pa + (size_t)(j * 8) * K, la + j * 512);
            g2lds16(pb + (size_t)(j * 8) * K, lb + j * 512);
        }
        pa += 64; pb += 64;
        __syncthreads();                        // drains vmcnt -> LDS valid

#pragma unroll
        for (int ks = 0; ks < 2; ++ks) {
            bf16x8 af[4], bf[4];
            const int c = ks * 4 + quad;        // logical chunk in row
            const int p = c ^ swz;              // physical chunk
#pragma unroll
            for (int i = 0; i < 4; ++i)
                af[i] = *(const bf16x8*)(ldsA + (wm + i * 16 + lhalf) * 64 + p * 8);
#pragma unroll
            for (int j = 0; j < 4; ++j)
                bf[j] = *(const bf16x8*)(ldsB + (wn + j * 16 + lhalf) * 64 + p * 8);
#pragma unroll
            for (int i = 0; i < 4; ++i)
#pragma unroll
                for (int j = 0; j < 4; ++j)
                    acc[i][j] = __builtin_amdgcn_mfma_f32_16x16x32_bf16(
                        af[i], bf[j], acc[i][j], 0, 0, 0);
        }
    }

    // epilogue: C/D layout col=lane&15 (n), row=quad*4+reg (m)  [m89/m91]
#pragma unroll
    for (int i = 0; i < 4; ++i) {
        const int mb = m0 + wm + i * 16 + quad * 4;
#pragma unroll
        for (int j = 0; j < 4; ++j) {
            const int n = n0 + wn + j * 16 + lhalf;
            const float bb = bias ? bias[n] : 0.f;
#pragma unroll
            for (int r = 0; r < 4; ++r) {
                const int m = mb + r;
                const float v = acc[i][j][r] * scale + bb;
                if (MODE == 2) {
                    ((float*)Out)[bz * (size_t)sOz + (size_t)m * N + n] = v;
                } else if (MODE == 0) {
                    ((u16*)Out)[bz * (size_t)sOz + (size_t)m * N + n] = f2bf(v);
                } else {
                    ((u16*)Out)[bz * (size_t)sOz + (size_t)n * M + m] = f2bf(v);
                }
            }
        }
    }
}

// ---------------- row softmax over 2048 bf16, in place ----------------
__global__ __launch_bounds__(256)
void softmax_rows(u16* __restrict__ S)
{
    const int tid = threadIdx.x;
    u16* row = S + (size_t)blockIdx.x * 2048;
    uint4 v = ((const uint4*)row)[tid];     // 8 bf16 per thread
    float x[8];
    x[0] = __uint_as_float(v.x << 16); x[1] = __uint_as_float(v.x & 0xffff0000u);
    x[2] = __uint_as_float(v.y << 16); x[3] = __uint_as_float(v.y & 0xffff0000u);
    x[4] = __uint_as_float(v.z << 16); x[5] = __uint_as_float(v.z & 0xffff0000u);
    x[6] = __uint_as_float(v.w << 16); x[7] = __uint_as_float(v.w & 0xffff0000u);

    float mx = x[0];
#pragma unroll
    for (int i = 1; i < 8; ++i) mx = fmaxf(mx, x[i]);
#pragma unroll
    for (int off = 32; off > 0; off >>= 1) mx = fmaxf(mx, __shfl_xor(mx, off, 64));

    __shared__ float sm[4], ss[4];
    if ((tid & 63) == 0) sm[tid >> 6] = mx;
    __syncthreads();
    mx = fmaxf(fmaxf(sm[0], sm[1]), fmaxf(sm[2], sm[3]));

    float e[8];
    float s = 0.f;
#pragma unroll
    for (int i = 0; i < 8; ++i) { e[i] = __expf(x[i] - mx); s += e[i]; }
#pragma unroll
    for (int off = 32; off > 0; off >>= 1) s += __shfl_xor(s, off, 64);
    if ((tid & 63) == 0) ss[tid >> 6] = s;
    __syncthreads();
    s = (ss[0] + ss[1]) + (ss[2] + ss[3]);

    const float inv = 1.f / s;
    uint4 o;
    o.x = (u32)f2bf(e[0] * inv) | ((u32)f2bf(e[1] * inv) << 16);
    o.y = (u32)f2bf(e[2] * inv) | ((u32)f2bf(e[3] * inv) << 16);
    o.z = (u32)f2bf(e[4] * inv) | ((u32)f2bf(e[5] * inv) << 16);
    o.w = (u32)f2bf(e[6] * inv) | ((u32)f2bf(e[7] * inv) << 16);
    ((uint4*)row)[tid] = o;
}

extern "C" void kernel_launch(void* const* d_in, const int* in_sizes, int n_in,
                              void* d_out, int out_size, void* d_ws, size_t ws_size,
                              hipStream_t stream)
{
    const float* x  = (const float*)d_in[0];
    const float* Wq = (const float*)d_in[1];
    const float* bq = (const float*)d_in[2];
    const float* Wk = (const float*)d_in[3];
    const float* bk = (const float*)d_in[4];
    const float* Wv = (const float*)d_in[5];
    const float* bv = (const float*)d_in[6];
    float* out = (float*)d_out;

    const int B = 4, S = 2048, D = 1024;
    const long long SD = (long long)S * D;       // 2097152
    const long long SS = (long long)S * S;       // 4194304
    const long long BSD = (long long)B * SD;     // 8388608
    const long long DD = (long long)D * D;       // 1048576

    // workspace layout (bf16 = u16), total ~102 MB
    u16* xb  = (u16*)d_ws;
    u16* wqb = xb  + BSD;
    u16* wkb = wqb + DD;
    u16* wvb = wkb + DD;
    u16* Qb  = wvb + DD;
    u16* Kb  = Qb  + BSD;
    u16* Vt  = Kb  + BSD;        // per-batch transposed: Vt[b][d][s]
    u16* Sc  = Vt  + BSD;        // scores/att bf16: [b][q][k]

    // K0: casts
    cvt_f32_bf16<<<dim3((int)(BSD / 4 / 256)), 256, 0, stream>>>(x,  xb,  (int)(BSD / 4));
    cvt_f32_bf16<<<dim3((int)(DD  / 4 / 256)), 256, 0, stream>>>(Wq, wqb, (int)(DD / 4));
    cvt_f32_bf16<<<dim3((int)(DD  / 4 / 256)), 256, 0, stream>>>(Wk, wkb, (int)(DD / 4));
    cvt_f32_bf16<<<dim3((int)(DD  / 4 / 256)), 256, 0, stream>>>(Wv, wvb, (int)(DD / 4));

    // K1: Q, K row-major bf16 (M=8192), V^T per batch
    gemm_bt<0><<<dim3(D / 128, (B * S) / 128, 1), 256, 0, stream>>>(
        xb, wqb, Qb, bq, 1.f, B * S, D, D, 0, 0, 0);
    gemm_bt<0><<<dim3(D / 128, (B * S) / 128, 1), 256, 0, stream>>>(
        xb, wkb, Kb, bk, 1.f, B * S, D, D, 0, 0, 0);
    gemm_bt<1><<<dim3(D / 128, S / 128, B), 256, 0, stream>>>(
        xb, wvb, Vt, bv, 1.f, S, D, D, SD, 0, SD);

    // K2: scores = Q K^T / sqrt(S)
    const float sc = 0.022097086912079608f;  // 1/sqrt(2048)
    gemm_bt<0><<<dim3(S / 128, S / 128, B), 256, 0, stream>>>(
        Qb, Kb, Sc, nullptr, sc, S, S, D, SD, SD, SS);

    // K3: softmax rows
    softmax_rows<<<dim3(B * S), 256, 0, stream>>>(Sc);

    // K4: out = att @ V  (A = att, B = Vt rows=d, K=S)
    gemm_bt<2><<<dim3(D / 128, S / 128, B), 256, 0, stream>>>(
        Sc, Vt, out, nullptr, 1.f, S, D, S, SS, SD, SD);
}

// Round 3
// 271.846 us; speedup vs baseline: 1.2420x; 1.0640x over previous
//
#include <hip/hip_runtime.h>

// self_attention: x(4,2048,1024) fp32; Q=xWq^T+bq, K=xWk^T+bk, V=xWv^T+bv
// logits = QK^T / sqrt(2048); out = softmax(logits) @ V
//
// R3: gemm_bt v3 — double-buffered LDS with stage-after-barrier. The R2
// structure exposed full load latency at every __syncthreads (s_waitcnt
// vmcnt(0) right after issuing global_load_lds). Now the prefetch for iter
// i+1 is issued right after iter i's barrier, so the drain at iter i+1's
// barrier has had a full compute phase (~300-400 cyc MFMA+ds_read) to
// complete. LDS 64 KB -> 2 blocks/CU (effective concurrency was already
// ~1.7, and we remove the drain m132 kept).
// Kept from R2: BK=64, XOR chunk swizzle (0 bank conflicts), GROUP_M=4.

typedef unsigned short u16;
typedef unsigned int u32;
typedef __bf16 bf16x8 __attribute__((ext_vector_type(8)));
typedef float floatx4 __attribute__((ext_vector_type(4)));

__device__ __forceinline__ u16 f2bf(float f) {
    u32 u = __float_as_uint(f);
    u += 0x7fffu + ((u >> 16) & 1u);   // RNE
    return (u16)(u >> 16);
}

__device__ __forceinline__ void g2lds16(const void* g, void* l) {
    __builtin_amdgcn_global_load_lds(
        (const __attribute__((address_space(1))) unsigned int*)g,
        (__attribute__((address_space(3))) unsigned int*)l,
        16, 0, 0);
}

// ---------------- cast fp32 -> bf16, 4 elems/thread ----------------
__global__ __launch_bounds__(256)
void cvt_f32_bf16(const float* __restrict__ in, u16* __restrict__ out, int n4) {
    int i = blockIdx.x * 256 + threadIdx.x;
    if (i >= n4) return;
    float4 v = ((const float4*)in)[i];
    ushort4 o;
    o.x = f2bf(v.x); o.y = f2bf(v.y); o.z = f2bf(v.z); o.w = f2bf(v.w);
    ((ushort4*)out)[i] = o;
}

// ---------------- GEMM: C[m][n] = sum_k A[m][k] * B[n][k] ----------------
// A: M x K row-major bf16, B: N x K row-major bf16 (B^T layout).
// MODE 0: bf16 out row-major. MODE 1: bf16 out transposed (out[n*M+m]).
// MODE 2: fp32 out row-major.   val = acc*scale + bias[n]
// 128x128 block tile, BK=64, 4 waves each 64x64 (4x4 of 16x16x32 MFMA).
// LDS rows 128 B; 16 B chunk at physical index p = c ^ (row&7) -> frag
// ds_read_b128 conflict-free. Double-buffered (2 x 32 KB).
template<int MODE>
__global__ __launch_bounds__(256)
void gemm_bt(const u16* __restrict__ A, const u16* __restrict__ B,
             void* __restrict__ Out, const float* __restrict__ bias,
             float scale, int M, int N, int K,
             long long sAz, long long sBz, long long sOz)
{
    __shared__ u16 ldsA[2][128 * 64];   // 2 x 16 KB
    __shared__ u16 ldsB[2][128 * 64];   // 2 x 16 KB

    const int tid   = threadIdx.x;
    const int lane  = tid & 63;
    const int wv    = tid >> 6;          // wave 0..3
    const int wm    = (wv >> 1) * 64;    // wave tile row offset
    const int wn    = (wv & 1) * 64;     // wave tile col offset
    const int lhalf = lane & 15;
    const int quad  = lane >> 4;

    const size_t bz = blockIdx.z;
    A += bz * (size_t)sAz;
    B += bz * (size_t)sBz;

    // supertile mapping (GROUP_M=4) for L2 tile reuse
    int tm, tn;
    {
        const int ntn = gridDim.x, ntm = gridDim.y;
        const int lin = blockIdx.y * ntn + blockIdx.x;
        const int GM = 4;
        const int width = GM * ntn;
        const int group = lin / width;
        const int first = group * GM;
        const int gsz   = (ntm - first) < GM ? (ntm - first) : GM;
        const int rem   = lin - group * width;
        tm = first + rem % gsz;
        tn = rem / gsz;
    }
    const int m0 = tm * 128;
    const int n0 = tn * 128;

    // staging: physical chunk P = wv*256 + j*64 + lane  (j = 0..3)
    //   row r = P>>3 = wv*32 + j*8 + (lane>>3), phys chunk p = lane&7
    //   global chunk g = p ^ (r&7) = (lane&7) ^ (lane>>3)
    const int r8 = lane >> 3;                   // 0..7
    const int gc = (lane & 7) ^ r8;             // swizzled source chunk
    const u16* pa = A + (size_t)(m0 + wv * 32 + r8) * K + gc * 8;
    const u16* pb = B + (size_t)(n0 + wv * 32 + r8) * K + gc * 8;
    const int lofs = wv * 2048;                 // wave-uniform LDS base

    floatx4 zero = {0.f, 0.f, 0.f, 0.f};
    floatx4 acc[4][4];
#pragma unroll
    for (int i = 0; i < 4; ++i)
#pragma unroll
        for (int j = 0; j < 4; ++j) acc[i][j] = zero;

    const int swz = lhalf & 7;                  // row&7 for all frag rows

    // prologue: stage iter 0 into buf 0
#pragma unroll
    for (int j = 0; j < 4; ++j) {
        g2lds16(pa + (size_t)(j * 8) * K, &ldsA[0][lofs + j * 512]);
        g2lds16(pb + (size_t)(j * 8) * K, &ldsB[0][lofs + j * 512]);
    }
    pa += 64; pb += 64;

    int buf = 0;
    for (int k0 = 0; k0 < K; k0 += 64) {
        // drains vmcnt(0): buf[buf]'s loads (issued one compute-phase ago)
        // done; lgkmcnt(0): all waves' prev reads of buf[buf^1] done.
        __syncthreads();
        if (k0 + 64 < K) {
#pragma unroll
            for (int j = 0; j < 4; ++j) {
                g2lds16(pa + (size_t)(j * 8) * K, &ldsA[buf ^ 1][lofs + j * 512]);
                g2lds16(pb + (size_t)(j * 8) * K, &ldsB[buf ^ 1][lofs + j * 512]);
            }
            pa += 64; pb += 64;
        }

        const u16* lA = ldsA[buf];
        const u16* lB = ldsB[buf];
#pragma unroll
        for (int ks = 0; ks < 2; ++ks) {
            bf16x8 af[4], bfv[4];
            const int c = ks * 4 + quad;        // logical chunk in row
            const int p = c ^ swz;              // physical chunk
#pragma unroll
            for (int i = 0; i < 4; ++i)
                af[i] = *(const bf16x8*)(lA + (wm + i * 16 + lhalf) * 64 + p * 8);
#pragma unroll
            for (int j = 0; j < 4; ++j)
                bfv[j] = *(const bf16x8*)(lB + (wn + j * 16 + lhalf) * 64 + p * 8);
#pragma unroll
            for (int i = 0; i < 4; ++i)
#pragma unroll
                for (int j = 0; j < 4; ++j)
                    acc[i][j] = __builtin_amdgcn_mfma_f32_16x16x32_bf16(
                        af[i], bfv[j], acc[i][j], 0, 0, 0);
        }
        buf ^= 1;
    }

    // epilogue: C/D layout col=lane&15 (n), row=quad*4+reg (m)  [m89/m91]
#pragma unroll
    for (int i = 0; i < 4; ++i) {
        const int mb = m0 + wm + i * 16 + quad * 4;
#pragma unroll
        for (int j = 0; j < 4; ++j) {
            const int n = n0 + wn + j * 16 + lhalf;
            const float bb = bias ? bias[n] : 0.f;
#pragma unroll
            for (int r = 0; r < 4; ++r) {
                const int m = mb + r;
                const float v = acc[i][j][r] * scale + bb;
                if (MODE == 2) {
                    ((float*)Out)[bz * (size_t)sOz + (size_t)m * N + n] = v;
                } else if (MODE == 0) {
                    ((u16*)Out)[bz * (size_t)sOz + (size_t)m * N + n] = f2bf(v);
                } else {
                    ((u16*)Out)[bz * (size_t)sOz + (size_t)n * M + m] = f2bf(v);
                }
            }
        }
    }
}

// ---------------- row softmax over 2048 bf16, in place ----------------
__global__ __launch_bounds__(256)
void softmax_rows(u16* __restrict__ S)
{
    const int tid = threadIdx.x;
    u16* row = S + (size_t)blockIdx.x * 2048;
    uint4 v = ((const uint4*)row)[tid];     // 8 bf16 per thread
    float x[8];
    x[0] = __uint_as_float(v.x << 16); x[1] = __uint_as_float(v.x & 0xffff0000u);
    x[2] = __uint_as_float(v.y << 16); x[3] = __uint_as_float(v.y & 0xffff0000u);
    x[4] = __uint_as_float(v.z << 16); x[5] = __uint_as_float(v.z & 0xffff0000u);
    x[6] = __uint_as_float(v.w << 16); x[7] = __uint_as_float(v.w & 0xffff0000u);

    float mx = x[0];
#pragma unroll
    for (int i = 1; i < 8; ++i) mx = fmaxf(mx, x[i]);
#pragma unroll
    for (int off = 32; off > 0; off >>= 1) mx = fmaxf(mx, __shfl_xor(mx, off, 64));

    __shared__ float sm[4], ss[4];
    if ((tid & 63) == 0) sm[tid >> 6] = mx;
    __syncthreads();
    mx = fmaxf(fmaxf(sm[0], sm[1]), fmaxf(sm[2], sm[3]));

    float e[8];
    float s = 0.f;
#pragma unroll
    for (int i = 0; i < 8; ++i) { e[i] = __expf(x[i] - mx); s += e[i]; }
#pragma unroll
    for (int off = 32; off > 0; off >>= 1) s += __shfl_xor(s, off, 64);
    if ((tid & 63) == 0) ss[tid >> 6] = s;
    __syncthreads();
    s = (ss[0] + ss[1]) + (ss[2] + ss[3]);

    const float inv = 1.f / s;
    uint4 o;
    o.x = (u32)f2bf(e[0] * inv) | ((u32)f2bf(e[1] * inv) << 16);
    o.y = (u32)f2bf(e[2] * inv) | ((u32)f2bf(e[3] * inv) << 16);
    o.z = (u32)f2bf(e[4] * inv) | ((u32)f2bf(e[5] * inv) << 16);
    o.w = (u32)f2bf(e[6] * inv) | ((u32)f2bf(e[7] * inv) << 16);
    ((uint4*)row)[tid] = o;
}

extern "C" void kernel_launch(void* const* d_in, const int* in_sizes, int n_in,
                              void* d_out, int out_size, void* d_ws, size_t ws_size,
                              hipStream_t stream)
{
    const float* x  = (const float*)d_in[0];
    const float* Wq = (const float*)d_in[1];
    const float* bq = (const float*)d_in[2];
    const float* Wk = (const float*)d_in[3];
    const float* bk = (const float*)d_in[4];
    const float* Wv = (const float*)d_in[5];
    const float* bv = (const float*)d_in[6];
    float* out = (float*)d_out;

    const int B = 4, S = 2048, D = 1024;
    const long long SD = (long long)S * D;       // 2097152
    const long long SS = (long long)S * S;       // 4194304
    const long long BSD = (long long)B * SD;     // 8388608
    const long long DD = (long long)D * D;       // 1048576

    // workspace layout (bf16 = u16), total ~102 MB
    u16* xb  = (u16*)d_ws;
    u16* wqb = xb  + BSD;
    u16* wkb = wqb + DD;
    u16* wvb = wkb + DD;
    u16* Qb  = wvb + DD;
    u16* Kb  = Qb  + BSD;
    u16* Vt  = Kb  + BSD;        // per-batch transposed: Vt[b][d][s]
    u16* Sc  = Vt  + BSD;        // scores/att bf16: [b][q][k]

    // K0: casts
    cvt_f32_bf16<<<dim3((int)(BSD / 4 / 256)), 256, 0, stream>>>(x,  xb,  (int)(BSD / 4));
    cvt_f32_bf16<<<dim3((int)(DD  / 4 / 256)), 256, 0, stream>>>(Wq, wqb, (int)(DD / 4));
    cvt_f32_bf16<<<dim3((int)(DD  / 4 / 256)), 256, 0, stream>>>(Wk, wkb, (int)(DD / 4));
    cvt_f32_bf16<<<dim3((int)(DD  / 4 / 256)), 256, 0, stream>>>(Wv, wvb, (int)(DD / 4));

    // K1: Q, K row-major bf16 (M=8192), V^T per batch
    gemm_bt<0><<<dim3(D / 128, (B * S) / 128, 1), 256, 0, stream>>>(
        xb, wqb, Qb, bq, 1.f, B * S, D, D, 0, 0, 0);
    gemm_bt<0><<<dim3(D / 128, (B * S) / 128, 1), 256, 0, stream>>>(
        xb, wkb, Kb, bk, 1.f, B * S, D, D, 0, 0, 0);
    gemm_bt<1><<<dim3(D / 128, S / 128, B), 256, 0, stream>>>(
        xb, wvb, Vt, bv, 1.f, S, D, D, SD, 0, SD);

    // K2: scores = Q K^T / sqrt(S)
    const float sc = 0.022097086912079608f;  // 1/sqrt(2048)
    gemm_bt<0><<<dim3(S / 128, S / 128, B), 256, 0, stream>>>(
        Qb, Kb, Sc, nullptr, sc, S, S, D, SD, SD, SS);

    // K3: softmax rows
    softmax_rows<<<dim3(B * S), 256, 0, stream>>>(Sc);

    // K4: out = att @ V  (A = att, B = Vt rows=d, K=S)
    gemm_bt<2><<<dim3(D / 128, S / 128, B), 256, 0, stream>>>(
        Sc, Vt, out, nullptr, 1.f, S, D, S, SS, SD, SD);
}